// Round 1
// baseline (2045.193 us; speedup 1.0000x reference)
//
#include <hip/hip_runtime.h>
#include <cstdint>
#include <cstddef>

#define NN 100000
#define EE 400000
#define CC 16
#define LL 16

// ---------- device helpers ----------
__device__ __forceinline__ float lrelu(float v){ return v > 0.0f ? v : 0.01f*v; }

__device__ __forceinline__ float waveSum(float v){
#pragma unroll
  for (int off = 32; off >= 1; off >>= 1) v += __shfl_xor(v, off);
  return v;
}

__device__ __forceinline__ float fma4(float4 w, float4 v, float a){
  a = fmaf(w.x, v.x, a); a = fmaf(w.y, v.y, a);
  a = fmaf(w.z, v.z, a); a = fmaf(w.w, v.w, a);
  return a;
}

// ---------- init: count degrees + scatter edge features to both endpoints ----------
__global__ __launch_bounds__(256) void k_count(const int* __restrict__ ei,
    const float* __restrict__ ef, int* __restrict__ cdst, int* __restrict__ call,
    float* __restrict__ x0)
{
  int t = blockIdx.x*256 + threadIdx.x;
  if (t >= EE) return;
  int s = ei[t], d = ei[EE + t];
  atomicAdd(&cdst[d], 1);
  atomicAdd(&call[s], 1);
  atomicAdd(&call[d], 1);
  const float4* f4 = (const float4*)(ef + (size_t)t*CC);
  float4 ff[4];
  ff[0]=f4[0]; ff[1]=f4[1]; ff[2]=f4[2]; ff[3]=f4[3];
  float* xs = x0 + (size_t)s*CC;
  float* xd = x0 + (size_t)d*CC;
#pragma unroll
  for (int q=0;q<4;q++){
    unsafeAtomicAdd(xs+4*q+0, ff[q].x); unsafeAtomicAdd(xd+4*q+0, ff[q].x);
    unsafeAtomicAdd(xs+4*q+1, ff[q].y); unsafeAtomicAdd(xd+4*q+1, ff[q].y);
    unsafeAtomicAdd(xs+4*q+2, ff[q].z); unsafeAtomicAdd(xd+4*q+2, ff[q].z);
    unsafeAtomicAdd(xs+4*q+3, ff[q].w); unsafeAtomicAdd(xd+4*q+3, ff[q].w);
  }
}

// ---------- exclusive scan over N counts (3 kernels, SEG=1024) ----------
__global__ __launch_bounds__(256) void k_scan1(const int* __restrict__ cnt,
    int* __restrict__ rp, int* __restrict__ bsums)
{
  __shared__ int sd[256];
  int tid = threadIdx.x;
  int base = blockIdx.x*1024 + tid*4;
  int v0=0,v1=0,v2=0,v3=0;
  if (base+0 < NN) v0 = cnt[base+0];
  if (base+1 < NN) v1 = cnt[base+1];
  if (base+2 < NN) v2 = cnt[base+2];
  if (base+3 < NN) v3 = cnt[base+3];
  int tot = v0+v1+v2+v3;
  sd[tid] = tot; __syncthreads();
  for (int off=1; off<256; off<<=1){
    int add = (tid>=off) ? sd[tid-off] : 0;
    __syncthreads();
    sd[tid] += add;
    __syncthreads();
  }
  int excl = sd[tid] - tot;
  if (base+0 < NN) rp[base+0] = excl;
  if (base+1 < NN) rp[base+1] = excl+v0;
  if (base+2 < NN) rp[base+2] = excl+v0+v1;
  if (base+3 < NN) rp[base+3] = excl+v0+v1+v2;
  if (tid==255) bsums[blockIdx.x] = sd[255];
}

__global__ __launch_bounds__(256) void k_scan2(const int* __restrict__ bsums,
    int* __restrict__ boff, int n)
{
  __shared__ int sd[256];
  int tid = threadIdx.x;
  int v = (tid < n) ? bsums[tid] : 0;
  sd[tid] = v; __syncthreads();
  for (int off=1; off<256; off<<=1){
    int add = (tid>=off) ? sd[tid-off] : 0;
    __syncthreads();
    sd[tid] += add;
    __syncthreads();
  }
  if (tid < n) boff[tid] = sd[tid] - v;
}

__global__ __launch_bounds__(256) void k_scan3(int* __restrict__ rp,
    int* __restrict__ cur, const int* __restrict__ boff)
{
  int add = boff[blockIdx.x];
  int base = blockIdx.x*1024 + threadIdx.x*4;
#pragma unroll
  for (int i=0;i<4;i++){
    if (base+i < NN){ int v = rp[base+i] + add; rp[base+i] = v; cur[base+i] = v; }
  }
  if (blockIdx.x==0 && threadIdx.x==0) rp[NN] = EE;
}

__global__ __launch_bounds__(256) void k_fill(const int* __restrict__ ei,
    int* __restrict__ cur, int* __restrict__ list)
{
  int t = blockIdx.x*256 + threadIdx.x;
  if (t >= EE) return;
  int d = ei[EE + t];
  int p = atomicAdd(&cur[d], 1);
  list[p] = t;
}

// x0 /= clip(deg,1);  invdeg = 1/clip(deg_in,1)
__global__ __launch_bounds__(256) void k_norm0(float* __restrict__ x0,
    const int* __restrict__ call, const int* __restrict__ cdst,
    float* __restrict__ invdeg)
{
  int t = blockIdx.x*256 + threadIdx.x;
  if (t >= NN*CC) return;
  int n = t >> 4, c = t & 15;
  float dg = fmaxf((float)call[n], 1.0f);
  x0[t] = x0[t] / dg;
  if (c == 0) invdeg[n] = 1.0f / fmaxf((float)cdst[n], 1.0f);
}

// ---------- per-layer: m = W @ cat(x[dst],x[src]) + b, accumulate BN stats ----------
__global__ __launch_bounds__(256) void k_edge(const float* __restrict__ x,
    const int* __restrict__ ei, const float* __restrict__ W, const float* __restrict__ b,
    float* __restrict__ m, double* __restrict__ st)
{
  __shared__ float sW[512];
  __shared__ float sb16[16];
  __shared__ float sredS[64], sredQ[64];
  for (int i=threadIdx.x; i<512; i+=256) sW[i] = W[i];
  if (threadIdx.x < 16) sb16[threadIdx.x] = b[threadIdx.x];
  __syncthreads();

  int t = blockIdx.x*256 + threadIdx.x;
  int e0 = 2*t, e1 = 2*t+1;
  bool val = (e1 < EE);
  float acc0[16], acc1[16];
  if (val){
    int s0 = ei[e0], d0 = ei[EE+e0], s1 = ei[e1], d1 = ei[EE+e1];
    float4 xc0[8], xc1[8];
    const float4* p;
    p = (const float4*)(x + (size_t)d0*CC); xc0[0]=p[0]; xc0[1]=p[1]; xc0[2]=p[2]; xc0[3]=p[3];
    p = (const float4*)(x + (size_t)s0*CC); xc0[4]=p[0]; xc0[5]=p[1]; xc0[6]=p[2]; xc0[7]=p[3];
    p = (const float4*)(x + (size_t)d1*CC); xc1[0]=p[0]; xc1[1]=p[1]; xc1[2]=p[2]; xc1[3]=p[3];
    p = (const float4*)(x + (size_t)s1*CC); xc1[4]=p[0]; xc1[5]=p[1]; xc1[6]=p[2]; xc1[7]=p[3];
#pragma unroll
    for (int c=0;c<CC;c++){
      const float4* wr = (const float4*)(sW + c*32);
      float a0 = sb16[c], a1 = sb16[c];
#pragma unroll
      for (int q=0;q<8;q++){
        float4 w = wr[q];
        a0 = fma4(w, xc0[q], a0);
        a1 = fma4(w, xc1[q], a1);
      }
      acc0[c]=a0; acc1[c]=a1;
    }
    float4* mo0 = (float4*)(m + (size_t)e0*CC);
    float4* mo1 = (float4*)(m + (size_t)e1*CC);
    mo0[0]=make_float4(acc0[0],acc0[1],acc0[2],acc0[3]);
    mo0[1]=make_float4(acc0[4],acc0[5],acc0[6],acc0[7]);
    mo0[2]=make_float4(acc0[8],acc0[9],acc0[10],acc0[11]);
    mo0[3]=make_float4(acc0[12],acc0[13],acc0[14],acc0[15]);
    mo1[0]=make_float4(acc1[0],acc1[1],acc1[2],acc1[3]);
    mo1[1]=make_float4(acc1[4],acc1[5],acc1[6],acc1[7]);
    mo1[2]=make_float4(acc1[8],acc1[9],acc1[10],acc1[11]);
    mo1[3]=make_float4(acc1[12],acc1[13],acc1[14],acc1[15]);
  } else {
#pragma unroll
    for (int c=0;c<CC;c++){ acc0[c]=0.0f; acc1[c]=0.0f; }
  }

  int lane = threadIdx.x & 63, w = threadIdx.x >> 6;
#pragma unroll
  for (int c=0;c<CC;c++){
    float rs = acc0[c] + acc1[c];
    float rq = acc0[c]*acc0[c] + acc1[c]*acc1[c];
    rs = waveSum(rs); rq = waveSum(rq);
    if (lane == 0){ sredS[w*16+c] = rs; sredQ[w*16+c] = rq; }
  }
  __syncthreads();
  if (threadIdx.x < 16){
    int c = threadIdx.x;
    float tot = sredS[c] + sredS[16+c] + sredS[32+c] + sredS[48+c];
    unsafeAtomicAdd(&st[c], (double)tot);
  } else if (threadIdx.x < 32){
    int c = threadIdx.x - 16;
    float tot = sredQ[c] + sredQ[16+c] + sredQ[32+c] + sredQ[48+c];
    unsafeAtomicAdd(&st[16+c], (double)tot);
  }
}

// ---------- per-layer: finalize BN, leaky, CSR segment-mean by dst ----------
__global__ __launch_bounds__(256) void k_node(const float* __restrict__ m,
    const int* __restrict__ rp, const int* __restrict__ list,
    const float* __restrict__ invdeg, const double* __restrict__ st,
    const float* __restrict__ g, const float* __restrict__ bt,
    float* __restrict__ xout)
{
  __shared__ float sA[16], sB[16];
  if (threadIdx.x < 16){
    int c = threadIdx.x;
    double mu  = st[c] * (1.0/EE);
    double var = st[16+c] * (1.0/EE) - mu*mu;
    float sc = rsqrtf((float)var + 1e-5f);
    float A = sc * g[c];
    sA[c] = A; sB[c] = bt[c] - (float)mu * A;
  }
  __syncthreads();
  int t = blockIdx.x*256 + threadIdx.x;
  int n = t >> 4, c = t & 15;
  if (n >= NN) return;
  float A = sA[c], B = sB[c];
  int beg = rp[n], end = rp[n+1];
  float acc = 0.0f;
  for (int i=beg; i<end; i++){
    int e = list[i];
    acc += lrelu(fmaf(A, m[(size_t)e*CC + c], B));
  }
  xout[t] = acc * invdeg[n];
}

// ---------- final stage 1: BN stats over 2E rows (both orientations) ----------
__global__ __launch_bounds__(256) void k_final1(const float* __restrict__ x,
    const int* __restrict__ ei, const float* __restrict__ W, const float* __restrict__ b,
    double* __restrict__ st)
{
  __shared__ float sW[512];
  __shared__ float sb16[16];
  __shared__ float sredS[64], sredQ[64];
  for (int i=threadIdx.x; i<512; i+=256) sW[i] = W[i];
  if (threadIdx.x < 16) sb16[threadIdx.x] = b[threadIdx.x];
  __syncthreads();

  int t = blockIdx.x*256 + threadIdx.x;
  bool val = (t < EE);
  float af[16], ab[16];
  if (val){
    int s = ei[t], d = ei[EE+t];
    float4 xs[4], xd[4];
    const float4* p;
    p = (const float4*)(x + (size_t)s*CC); xs[0]=p[0]; xs[1]=p[1]; xs[2]=p[2]; xs[3]=p[3];
    p = (const float4*)(x + (size_t)d*CC); xd[0]=p[0]; xd[1]=p[1]; xd[2]=p[2]; xd[3]=p[3];
#pragma unroll
    for (int c=0;c<CC;c++){
      const float4* wr = (const float4*)(sW + c*32);
      float f = sb16[c], g_ = sb16[c];
#pragma unroll
      for (int q=0;q<4;q++){ float4 w = wr[q];   f = fma4(w, xs[q], f);  g_ = fma4(w, xd[q], g_); }
#pragma unroll
      for (int q=0;q<4;q++){ float4 w = wr[4+q]; f = fma4(w, xd[q], f);  g_ = fma4(w, xs[q], g_); }
      af[c]=f; ab[c]=g_;
    }
  } else {
#pragma unroll
    for (int c=0;c<CC;c++){ af[c]=0.0f; ab[c]=0.0f; }
  }

  int lane = threadIdx.x & 63, w = threadIdx.x >> 6;
#pragma unroll
  for (int c=0;c<CC;c++){
    float rs = af[c] + ab[c];
    float rq = af[c]*af[c] + ab[c]*ab[c];
    rs = waveSum(rs); rq = waveSum(rq);
    if (lane == 0){ sredS[w*16+c] = rs; sredQ[w*16+c] = rq; }
  }
  __syncthreads();
  if (threadIdx.x < 16){
    int c = threadIdx.x;
    float tot = sredS[c] + sredS[16+c] + sredS[32+c] + sredS[48+c];
    unsafeAtomicAdd(&st[c], (double)tot);
  } else if (threadIdx.x < 32){
    int c = threadIdx.x - 16;
    float tot = sredQ[c] + sredQ[16+c] + sredQ[32+c] + sredQ[48+c];
    unsafeAtomicAdd(&st[16+c], (double)tot);
  }
}

// ---------- final stage 2: recompute, BN+leaky, edge_out + loss accumulation ----------
__global__ __launch_bounds__(256) void k_final2(const float* __restrict__ x,
    const int* __restrict__ ei, const float* __restrict__ W, const float* __restrict__ b,
    const double* __restrict__ st, const float* __restrict__ g, const float* __restrict__ bt,
    float* __restrict__ out, double* __restrict__ loss)
{
  __shared__ float sW[512];
  __shared__ float sb16[16];
  __shared__ float sA[16], sB[16];
  __shared__ float sl[4];
  for (int i=threadIdx.x; i<512; i+=256) sW[i] = W[i];
  if (threadIdx.x < 16){
    int c = threadIdx.x;
    sb16[c] = b[c];
    double mu  = st[c] * (1.0/(2.0*EE));
    double var = st[16+c] * (1.0/(2.0*EE)) - mu*mu;
    float sc = rsqrtf((float)var + 1e-5f);
    float A = sc * g[c];
    sA[c] = A; sB[c] = bt[c] - (float)mu * A;
  }
  __syncthreads();

  int t = blockIdx.x*256 + threadIdx.x;
  bool val = (t < EE);
  float lsum = 0.0f;
  if (val){
    int s = ei[t], d = ei[EE+t];
    float4 xs[4], xd[4];
    const float4* p;
    p = (const float4*)(x + (size_t)s*CC); xs[0]=p[0]; xs[1]=p[1]; xs[2]=p[2]; xs[3]=p[3];
    p = (const float4*)(x + (size_t)d*CC); xd[0]=p[0]; xd[1]=p[1]; xd[2]=p[2]; xd[3]=p[3];
    float fo[16];
#pragma unroll
    for (int c=0;c<CC;c++){
      const float4* wr = (const float4*)(sW + c*32);
      float f = sb16[c], g_ = sb16[c];
#pragma unroll
      for (int q=0;q<4;q++){ float4 w = wr[q];   f = fma4(w, xs[q], f);  g_ = fma4(w, xd[q], g_); }
#pragma unroll
      for (int q=0;q<4;q++){ float4 w = wr[4+q]; f = fma4(w, xd[q], f);  g_ = fma4(w, xs[q], g_); }
      float efv = lrelu(fmaf(sA[c], f,  sB[c]));
      float ebv = lrelu(fmaf(sA[c], g_, sB[c]));
      fo[c] = 0.5f*(efv + ebv);
      float dlt = efv - ebv;
      lsum = fmaf(dlt, dlt, lsum);
    }
    float4* po = (float4*)(out + (size_t)t*CC);
    po[0]=make_float4(fo[0],fo[1],fo[2],fo[3]);
    po[1]=make_float4(fo[4],fo[5],fo[6],fo[7]);
    po[2]=make_float4(fo[8],fo[9],fo[10],fo[11]);
    po[3]=make_float4(fo[12],fo[13],fo[14],fo[15]);
  }
  lsum = waveSum(lsum);
  int lane = threadIdx.x & 63, w = threadIdx.x >> 6;
  if (lane == 0) sl[w] = lsum;
  __syncthreads();
  if (threadIdx.x == 0)
    unsafeAtomicAdd(loss, (double)(sl[0]+sl[1]+sl[2]+sl[3]));
}

__global__ void k_final3(float* __restrict__ out, const double* __restrict__ loss)
{
  out[(size_t)EE*CC] = (float)(loss[0] * (1.0/((double)EE*CC)));
}

// ---------- host ----------
extern "C" void kernel_launch(void* const* d_in, const int* in_sizes, int n_in,
                              void* d_out, int out_size, void* d_ws, size_t ws_size,
                              hipStream_t stream)
{
  (void)in_sizes; (void)n_in; (void)out_size; (void)ws_size;
  const float* ef  = (const float*)d_in[0];
  const int*   ei  = (const int*)d_in[1];
  // d_in[2] = angles (unused by reference forward)
  const float* Wn  = (const float*)d_in[3];
  const float* bn  = (const float*)d_in[4];
  const float* gn  = (const float*)d_in[5];
  const float* btn = (const float*)d_in[6];
  const float* We  = (const float*)d_in[7];
  const float* be  = (const float*)d_in[8];
  const float* ge  = (const float*)d_in[9];
  const float* bte = (const float*)d_in[10];
  float* out = (float*)d_out;
  char* ws = (char*)d_ws;

  size_t off = 0;
  auto alloc = [&](size_t bytes)->size_t{
    size_t r = off; off = (off + bytes + 255) & ~(size_t)255; return r;
  };
  size_t o_xa     = alloc((size_t)NN*CC*4);
  size_t o_xb     = alloc((size_t)NN*CC*4);
  size_t o_m      = alloc((size_t)EE*CC*4);
  size_t o_cdst   = alloc((size_t)NN*4);
  size_t o_call   = alloc((size_t)NN*4);
  size_t o_rp     = alloc((size_t)(NN+1)*4);
  size_t o_cur    = alloc((size_t)NN*4);
  size_t o_list   = alloc((size_t)EE*4);
  size_t o_bsum   = alloc(512);
  size_t o_boff   = alloc(512);
  size_t o_stats  = alloc(545*8);   // 17 slots * 32 doubles + 1 loss double
  size_t o_invdeg = alloc((size_t)NN*4);

  float*  x_a    = (float*)(ws + o_xa);
  float*  x_b    = (float*)(ws + o_xb);
  float*  m_hat  = (float*)(ws + o_m);
  int*    cdst   = (int*)(ws + o_cdst);
  int*    call_  = (int*)(ws + o_call);
  int*    rp     = (int*)(ws + o_rp);
  int*    cur    = (int*)(ws + o_cur);
  int*    list   = (int*)(ws + o_list);
  int*    bsum   = (int*)(ws + o_bsum);
  int*    boff   = (int*)(ws + o_boff);
  double* stats  = (double*)(ws + o_stats);
  double* lossd  = stats + 17*32;   // index 544
  float*  invdeg = (float*)(ws + o_invdeg);

  const int GB_E  = (EE + 255)/256;       // 1563
  const int GB_E2 = (EE/2 + 255)/256;     // 782
  const int GB_NC = (NN*CC + 255)/256;    // 6250
  const int NSEG  = (NN + 1023)/1024;     // 98

  hipMemsetAsync(x_a, 0, (size_t)NN*CC*4, stream);
  hipMemsetAsync(cdst, 0, (size_t)NN*4, stream);
  hipMemsetAsync(call_, 0, (size_t)NN*4, stream);
  hipMemsetAsync(stats, 0, 545*8, stream);

  k_count<<<GB_E, 256, 0, stream>>>(ei, ef, cdst, call_, x_a);
  k_scan1<<<NSEG, 256, 0, stream>>>(cdst, rp, bsum);
  k_scan2<<<1, 256, 0, stream>>>(bsum, boff, NSEG);
  k_scan3<<<NSEG, 256, 0, stream>>>(rp, cur, boff);
  k_fill <<<GB_E, 256, 0, stream>>>(ei, cur, list);
  k_norm0<<<GB_NC, 256, 0, stream>>>(x_a, call_, cdst, invdeg);

  const float* xc = x_a;
  float* xn = x_b;
  for (int l = 0; l < LL; ++l){
    double* st = stats + (size_t)l*32;
    k_edge<<<GB_E2, 256, 0, stream>>>(xc, ei, Wn + (size_t)l*CC*2*CC, bn + (size_t)l*CC, m_hat, st);
    k_node<<<GB_NC, 256, 0, stream>>>(m_hat, rp, list, invdeg, st, gn + (size_t)l*CC, btn + (size_t)l*CC, xn);
    float* tmp = (float*)xc; xc = xn; xn = tmp;
  }

  double* stF = stats + 16*32;
  k_final1<<<GB_E, 256, 0, stream>>>(xc, ei, We, be, stF);
  k_final2<<<GB_E, 256, 0, stream>>>(xc, ei, We, be, stF, ge, bte, out, lossd);
  k_final3<<<1, 1, 0, stream>>>(out, lossd);
}

// Round 2
// 1490.241 us; speedup vs baseline: 1.3724x; 1.3724x over previous
//
#include <hip/hip_runtime.h>
#include <cstdint>
#include <cstddef>

#define NN 100000
#define EE 400000
#define CC 16
#define LL 16

// ---------- device helpers ----------
__device__ __forceinline__ float lrelu(float v){ return v > 0.0f ? v : 0.01f*v; }

__device__ __forceinline__ float waveSum(float v){
#pragma unroll
  for (int off = 32; off >= 1; off >>= 1) v += __shfl_xor(v, off);
  return v;
}

__device__ __forceinline__ float fma4(float4 w, float4 v, float a){
  a = fmaf(w.x, v.x, a); a = fmaf(w.y, v.y, a);
  a = fmaf(w.z, v.z, a); a = fmaf(w.w, v.w, a);
  return a;
}

// ---------- init: count degrees (int atomics only) ----------
__global__ __launch_bounds__(256) void k_count(const int* __restrict__ ei,
    int* __restrict__ cdst, int* __restrict__ call)
{
  int t = blockIdx.x*256 + threadIdx.x;
  if (t >= EE) return;
  int s = ei[t], d = ei[EE + t];
  atomicAdd(&cdst[d], 1);
  atomicAdd(&call[s], 1);
  atomicAdd(&call[d], 1);
}

// ---------- generic exclusive scan (SEG=1024/block, single pass level-2) ----------
__global__ __launch_bounds__(256) void k_scan1(const int* __restrict__ cnt,
    int* __restrict__ rp, int* __restrict__ bsums, int n)
{
  __shared__ int sd[256];
  int tid = threadIdx.x;
  int base = blockIdx.x*1024 + tid*4;
  int v0=0,v1=0,v2=0,v3=0;
  if (base+0 < n) v0 = cnt[base+0];
  if (base+1 < n) v1 = cnt[base+1];
  if (base+2 < n) v2 = cnt[base+2];
  if (base+3 < n) v3 = cnt[base+3];
  int tot = v0+v1+v2+v3;
  sd[tid] = tot; __syncthreads();
  for (int off=1; off<256; off<<=1){
    int add = (tid>=off) ? sd[tid-off] : 0;
    __syncthreads();
    sd[tid] += add;
    __syncthreads();
  }
  int excl = sd[tid] - tot;
  if (base+0 < n) rp[base+0] = excl;
  if (base+1 < n) rp[base+1] = excl+v0;
  if (base+2 < n) rp[base+2] = excl+v0+v1;
  if (base+3 < n) rp[base+3] = excl+v0+v1+v2;
  if (tid==255) bsums[blockIdx.x] = sd[255];
}

__global__ __launch_bounds__(256) void k_scan2(const int* __restrict__ bsums,
    int* __restrict__ boff, int nseg)
{
  __shared__ int sd[256];
  int tid = threadIdx.x;
  int v = (tid < nseg) ? bsums[tid] : 0;
  sd[tid] = v; __syncthreads();
  for (int off=1; off<256; off<<=1){
    int add = (tid>=off) ? sd[tid-off] : 0;
    __syncthreads();
    sd[tid] += add;
    __syncthreads();
  }
  if (tid < nseg) boff[tid] = sd[tid] - v;
}

__global__ __launch_bounds__(256) void k_scan3(int* __restrict__ rp,
    int* __restrict__ cur, const int* __restrict__ boff, int n, int total)
{
  int add = boff[blockIdx.x];
  int base = blockIdx.x*1024 + threadIdx.x*4;
#pragma unroll
  for (int i=0;i<4;i++){
    if (base+i < n){ int v = rp[base+i] + add; rp[base+i] = v; cur[base+i] = v; }
  }
  if (blockIdx.x==0 && threadIdx.x==0) rp[n] = total;
}

// ---------- fill both CSRs ----------
__global__ __launch_bounds__(256) void k_fill(const int* __restrict__ ei,
    int* __restrict__ cur, int* __restrict__ list,
    int* __restrict__ cur_all, int* __restrict__ list_all)
{
  int t = blockIdx.x*256 + threadIdx.x;
  if (t >= EE) return;
  int s = ei[t], d = ei[EE + t];
  int p = atomicAdd(&cur[d], 1);
  list[p] = t;
  int pa = atomicAdd(&cur_all[s], 1);
  list_all[pa] = t;
  int pb = atomicAdd(&cur_all[d], 1);
  list_all[pb] = t;
}

// ---------- x0 = mean of incident edge features; invdeg = 1/clip(deg_in,1) ----------
__global__ __launch_bounds__(256) void k_gather0(const float* __restrict__ ef,
    const int* __restrict__ rp_all, const int* __restrict__ list_all,
    const int* __restrict__ rp, float* __restrict__ x0, float* __restrict__ invdeg)
{
  int t = blockIdx.x*256 + threadIdx.x;
  if (t >= NN*CC) return;
  int n = t >> 4, c = t & 15;
  int beg = rp_all[n], end = rp_all[n+1];
  float acc = 0.0f;
  for (int i=beg; i<end; i++){
    acc += ef[(size_t)list_all[i]*CC + c];
  }
  float dg = fmaxf((float)(end-beg), 1.0f);
  x0[t] = acc / dg;
  if (c == 0){
    int di = rp[n+1] - rp[n];
    invdeg[n] = 1.0f / fmaxf((float)di, 1.0f);
  }
}

// ---------- per-layer: m = W @ cat(x[dst],x[src]) + b, accumulate BN stats ----------
__global__ __launch_bounds__(256) void k_edge(const float* __restrict__ x,
    const int* __restrict__ ei, const float* __restrict__ W, const float* __restrict__ b,
    float* __restrict__ m, double* __restrict__ st)
{
  __shared__ float sW[512];
  __shared__ float sb16[16];
  __shared__ float sredS[64], sredQ[64];
  for (int i=threadIdx.x; i<512; i+=256) sW[i] = W[i];
  if (threadIdx.x < 16) sb16[threadIdx.x] = b[threadIdx.x];
  __syncthreads();

  int t = blockIdx.x*256 + threadIdx.x;
  int e0 = 2*t, e1 = 2*t+1;
  bool val = (e1 < EE);
  float acc0[16], acc1[16];
  if (val){
    int s0 = ei[e0], d0 = ei[EE+e0], s1 = ei[e1], d1 = ei[EE+e1];
    float4 xc0[8], xc1[8];
    const float4* p;
    p = (const float4*)(x + (size_t)d0*CC); xc0[0]=p[0]; xc0[1]=p[1]; xc0[2]=p[2]; xc0[3]=p[3];
    p = (const float4*)(x + (size_t)s0*CC); xc0[4]=p[0]; xc0[5]=p[1]; xc0[6]=p[2]; xc0[7]=p[3];
    p = (const float4*)(x + (size_t)d1*CC); xc1[0]=p[0]; xc1[1]=p[1]; xc1[2]=p[2]; xc1[3]=p[3];
    p = (const float4*)(x + (size_t)s1*CC); xc1[4]=p[0]; xc1[5]=p[1]; xc1[6]=p[2]; xc1[7]=p[3];
#pragma unroll
    for (int c=0;c<CC;c++){
      const float4* wr = (const float4*)(sW + c*32);
      float a0 = sb16[c], a1 = sb16[c];
#pragma unroll
      for (int q=0;q<8;q++){
        float4 w = wr[q];
        a0 = fma4(w, xc0[q], a0);
        a1 = fma4(w, xc1[q], a1);
      }
      acc0[c]=a0; acc1[c]=a1;
    }
    float4* mo0 = (float4*)(m + (size_t)e0*CC);
    float4* mo1 = (float4*)(m + (size_t)e1*CC);
    mo0[0]=make_float4(acc0[0],acc0[1],acc0[2],acc0[3]);
    mo0[1]=make_float4(acc0[4],acc0[5],acc0[6],acc0[7]);
    mo0[2]=make_float4(acc0[8],acc0[9],acc0[10],acc0[11]);
    mo0[3]=make_float4(acc0[12],acc0[13],acc0[14],acc0[15]);
    mo1[0]=make_float4(acc1[0],acc1[1],acc1[2],acc1[3]);
    mo1[1]=make_float4(acc1[4],acc1[5],acc1[6],acc1[7]);
    mo1[2]=make_float4(acc1[8],acc1[9],acc1[10],acc1[11]);
    mo1[3]=make_float4(acc1[12],acc1[13],acc1[14],acc1[15]);
  } else {
#pragma unroll
    for (int c=0;c<CC;c++){ acc0[c]=0.0f; acc1[c]=0.0f; }
  }

  int lane = threadIdx.x & 63, w = threadIdx.x >> 6;
#pragma unroll
  for (int c=0;c<CC;c++){
    float rs = acc0[c] + acc1[c];
    float rq = acc0[c]*acc0[c] + acc1[c]*acc1[c];
    rs = waveSum(rs); rq = waveSum(rq);
    if (lane == 0){ sredS[w*16+c] = rs; sredQ[w*16+c] = rq; }
  }
  __syncthreads();
  if (threadIdx.x < 16){
    int c = threadIdx.x;
    float tot = sredS[c] + sredS[16+c] + sredS[32+c] + sredS[48+c];
    unsafeAtomicAdd(&st[c], (double)tot);
  } else if (threadIdx.x < 32){
    int c = threadIdx.x - 16;
    float tot = sredQ[c] + sredQ[16+c] + sredQ[32+c] + sredQ[48+c];
    unsafeAtomicAdd(&st[16+c], (double)tot);
  }
}

// ---------- per-layer: finalize BN, leaky, CSR segment-mean by dst ----------
__global__ __launch_bounds__(256) void k_node(const float* __restrict__ m,
    const int* __restrict__ rp, const int* __restrict__ list,
    const float* __restrict__ invdeg, const double* __restrict__ st,
    const float* __restrict__ g, const float* __restrict__ bt,
    float* __restrict__ xout)
{
  __shared__ float sA[16], sB[16];
  if (threadIdx.x < 16){
    int c = threadIdx.x;
    double mu  = st[c] * (1.0/EE);
    double var = st[16+c] * (1.0/EE) - mu*mu;
    float sc = rsqrtf((float)var + 1e-5f);
    float A = sc * g[c];
    sA[c] = A; sB[c] = bt[c] - (float)mu * A;
  }
  __syncthreads();
  int t = blockIdx.x*256 + threadIdx.x;
  int n = t >> 4, c = t & 15;
  if (n >= NN) return;
  float A = sA[c], B = sB[c];
  int beg = rp[n], end = rp[n+1];
  float acc = 0.0f;
  for (int i=beg; i<end; i++){
    int e = list[i];
    acc += lrelu(fmaf(A, m[(size_t)e*CC + c], B));
  }
  xout[t] = acc * invdeg[n];
}

// ---------- final stage 1: BN stats over 2E rows (both orientations) ----------
__global__ __launch_bounds__(256) void k_final1(const float* __restrict__ x,
    const int* __restrict__ ei, const float* __restrict__ W, const float* __restrict__ b,
    double* __restrict__ st)
{
  __shared__ float sW[512];
  __shared__ float sb16[16];
  __shared__ float sredS[64], sredQ[64];
  for (int i=threadIdx.x; i<512; i+=256) sW[i] = W[i];
  if (threadIdx.x < 16) sb16[threadIdx.x] = b[threadIdx.x];
  __syncthreads();

  int t = blockIdx.x*256 + threadIdx.x;
  bool val = (t < EE);
  float af[16], ab[16];
  if (val){
    int s = ei[t], d = ei[EE+t];
    float4 xs[4], xd[4];
    const float4* p;
    p = (const float4*)(x + (size_t)s*CC); xs[0]=p[0]; xs[1]=p[1]; xs[2]=p[2]; xs[3]=p[3];
    p = (const float4*)(x + (size_t)d*CC); xd[0]=p[0]; xd[1]=p[1]; xd[2]=p[2]; xd[3]=p[3];
#pragma unroll
    for (int c=0;c<CC;c++){
      const float4* wr = (const float4*)(sW + c*32);
      float f = sb16[c], g_ = sb16[c];
#pragma unroll
      for (int q=0;q<4;q++){ float4 w = wr[q];   f = fma4(w, xs[q], f);  g_ = fma4(w, xd[q], g_); }
#pragma unroll
      for (int q=0;q<4;q++){ float4 w = wr[4+q]; f = fma4(w, xd[q], f);  g_ = fma4(w, xs[q], g_); }
      af[c]=f; ab[c]=g_;
    }
  } else {
#pragma unroll
    for (int c=0;c<CC;c++){ af[c]=0.0f; ab[c]=0.0f; }
  }

  int lane = threadIdx.x & 63, w = threadIdx.x >> 6;
#pragma unroll
  for (int c=0;c<CC;c++){
    float rs = af[c] + ab[c];
    float rq = af[c]*af[c] + ab[c]*ab[c];
    rs = waveSum(rs); rq = waveSum(rq);
    if (lane == 0){ sredS[w*16+c] = rs; sredQ[w*16+c] = rq; }
  }
  __syncthreads();
  if (threadIdx.x < 16){
    int c = threadIdx.x;
    float tot = sredS[c] + sredS[16+c] + sredS[32+c] + sredS[48+c];
    unsafeAtomicAdd(&st[c], (double)tot);
  } else if (threadIdx.x < 32){
    int c = threadIdx.x - 16;
    float tot = sredQ[c] + sredQ[16+c] + sredQ[32+c] + sredQ[48+c];
    unsafeAtomicAdd(&st[16+c], (double)tot);
  }
}

// ---------- final stage 2: recompute, BN+leaky, edge_out + loss accumulation ----------
__global__ __launch_bounds__(256) void k_final2(const float* __restrict__ x,
    const int* __restrict__ ei, const float* __restrict__ W, const float* __restrict__ b,
    const double* __restrict__ st, const float* __restrict__ g, const float* __restrict__ bt,
    float* __restrict__ out, double* __restrict__ loss)
{
  __shared__ float sW[512];
  __shared__ float sb16[16];
  __shared__ float sA[16], sB[16];
  __shared__ float sl[4];
  for (int i=threadIdx.x; i<512; i+=256) sW[i] = W[i];
  if (threadIdx.x < 16){
    int c = threadIdx.x;
    sb16[c] = b[c];
    double mu  = st[c] * (1.0/(2.0*EE));
    double var = st[16+c] * (1.0/(2.0*EE)) - mu*mu;
    float sc = rsqrtf((float)var + 1e-5f);
    float A = sc * g[c];
    sA[c] = A; sB[c] = bt[c] - (float)mu * A;
  }
  __syncthreads();

  int t = blockIdx.x*256 + threadIdx.x;
  bool val = (t < EE);
  float lsum = 0.0f;
  if (val){
    int s = ei[t], d = ei[EE+t];
    float4 xs[4], xd[4];
    const float4* p;
    p = (const float4*)(x + (size_t)s*CC); xs[0]=p[0]; xs[1]=p[1]; xs[2]=p[2]; xs[3]=p[3];
    p = (const float4*)(x + (size_t)d*CC); xd[0]=p[0]; xd[1]=p[1]; xd[2]=p[2]; xd[3]=p[3];
    float fo[16];
#pragma unroll
    for (int c=0;c<CC;c++){
      const float4* wr = (const float4*)(sW + c*32);
      float f = sb16[c], g_ = sb16[c];
#pragma unroll
      for (int q=0;q<4;q++){ float4 w = wr[q];   f = fma4(w, xs[q], f);  g_ = fma4(w, xd[q], g_); }
#pragma unroll
      for (int q=0;q<4;q++){ float4 w = wr[4+q]; f = fma4(w, xd[q], f);  g_ = fma4(w, xs[q], g_); }
      float efv = lrelu(fmaf(sA[c], f,  sB[c]));
      float ebv = lrelu(fmaf(sA[c], g_, sB[c]));
      fo[c] = 0.5f*(efv + ebv);
      float dlt = efv - ebv;
      lsum = fmaf(dlt, dlt, lsum);
    }
    float4* po = (float4*)(out + (size_t)t*CC);
    po[0]=make_float4(fo[0],fo[1],fo[2],fo[3]);
    po[1]=make_float4(fo[4],fo[5],fo[6],fo[7]);
    po[2]=make_float4(fo[8],fo[9],fo[10],fo[11]);
    po[3]=make_float4(fo[12],fo[13],fo[14],fo[15]);
  }
  lsum = waveSum(lsum);
  int lane = threadIdx.x & 63, w = threadIdx.x >> 6;
  if (lane == 0) sl[w] = lsum;
  __syncthreads();
  if (threadIdx.x == 0)
    unsafeAtomicAdd(loss, (double)(sl[0]+sl[1]+sl[2]+sl[3]));
}

__global__ void k_final3(float* __restrict__ out, const double* __restrict__ loss)
{
  out[(size_t)EE*CC] = (float)(loss[0] * (1.0/((double)EE*CC)));
}

// ---------- host ----------
extern "C" void kernel_launch(void* const* d_in, const int* in_sizes, int n_in,
                              void* d_out, int out_size, void* d_ws, size_t ws_size,
                              hipStream_t stream)
{
  (void)in_sizes; (void)n_in; (void)out_size; (void)ws_size;
  const float* ef  = (const float*)d_in[0];
  const int*   ei  = (const int*)d_in[1];
  // d_in[2] = angles (unused by reference forward)
  const float* Wn  = (const float*)d_in[3];
  const float* bn  = (const float*)d_in[4];
  const float* gn  = (const float*)d_in[5];
  const float* btn = (const float*)d_in[6];
  const float* We  = (const float*)d_in[7];
  const float* be  = (const float*)d_in[8];
  const float* ge  = (const float*)d_in[9];
  const float* bte = (const float*)d_in[10];
  float* out = (float*)d_out;
  char* ws = (char*)d_ws;

  size_t off = 0;
  auto alloc = [&](size_t bytes)->size_t{
    size_t r = off; off = (off + bytes + 255) & ~(size_t)255; return r;
  };
  size_t o_xa     = alloc((size_t)NN*CC*4);
  size_t o_xb     = alloc((size_t)NN*CC*4);
  size_t o_m      = alloc((size_t)EE*CC*4);
  size_t o_cdst   = alloc((size_t)NN*4);
  size_t o_call   = alloc((size_t)NN*4);
  size_t o_rp     = alloc((size_t)(NN+1)*4);
  size_t o_rpall  = alloc((size_t)(NN+1)*4);
  size_t o_cur    = alloc((size_t)NN*4);
  size_t o_curall = alloc((size_t)NN*4);
  size_t o_list   = alloc((size_t)EE*4);
  size_t o_listall= alloc((size_t)2*EE*4);
  size_t o_bsum   = alloc(512);
  size_t o_boff   = alloc(512);
  size_t o_stats  = alloc(545*8);   // 17 slots * 32 doubles + 1 loss double
  size_t o_invdeg = alloc((size_t)NN*4);

  float*  x_a     = (float*)(ws + o_xa);
  float*  x_b     = (float*)(ws + o_xb);
  float*  m_hat   = (float*)(ws + o_m);
  int*    cdst    = (int*)(ws + o_cdst);
  int*    call_   = (int*)(ws + o_call);
  int*    rp      = (int*)(ws + o_rp);
  int*    rp_all  = (int*)(ws + o_rpall);
  int*    cur     = (int*)(ws + o_cur);
  int*    cur_all = (int*)(ws + o_curall);
  int*    list    = (int*)(ws + o_list);
  int*    list_all= (int*)(ws + o_listall);
  int*    bsum    = (int*)(ws + o_bsum);
  int*    boff    = (int*)(ws + o_boff);
  double* stats   = (double*)(ws + o_stats);
  double* lossd   = stats + 17*32;   // index 544
  float*  invdeg  = (float*)(ws + o_invdeg);

  const int GB_E  = (EE + 255)/256;       // 1563
  const int GB_E2 = (EE/2 + 255)/256;     // 782
  const int GB_NC = (NN*CC + 255)/256;    // 6250
  const int NSEG  = (NN + 1023)/1024;     // 98

  hipMemsetAsync(cdst, 0, (size_t)NN*4, stream);
  hipMemsetAsync(call_, 0, (size_t)NN*4, stream);
  hipMemsetAsync(stats, 0, 545*8, stream);

  k_count<<<GB_E, 256, 0, stream>>>(ei, cdst, call_);
  // dst CSR
  k_scan1<<<NSEG, 256, 0, stream>>>(cdst, rp, bsum, NN);
  k_scan2<<<1, 256, 0, stream>>>(bsum, boff, NSEG);
  k_scan3<<<NSEG, 256, 0, stream>>>(rp, cur, boff, NN, EE);
  // all CSR
  k_scan1<<<NSEG, 256, 0, stream>>>(call_, rp_all, bsum, NN);
  k_scan2<<<1, 256, 0, stream>>>(bsum, boff, NSEG);
  k_scan3<<<NSEG, 256, 0, stream>>>(rp_all, cur_all, boff, NN, 2*EE);
  // fill both lists
  k_fill<<<GB_E, 256, 0, stream>>>(ei, cur, list, cur_all, list_all);
  // initial node features (gather-mean) + invdeg
  k_gather0<<<GB_NC, 256, 0, stream>>>(ef, rp_all, list_all, rp, x_a, invdeg);

  const float* xc = x_a;
  float* xn = x_b;
  for (int l = 0; l < LL; ++l){
    double* st = stats + (size_t)l*32;
    k_edge<<<GB_E2, 256, 0, stream>>>(xc, ei, Wn + (size_t)l*CC*2*CC, bn + (size_t)l*CC, m_hat, st);
    k_node<<<GB_NC, 256, 0, stream>>>(m_hat, rp, list, invdeg, st, gn + (size_t)l*CC, btn + (size_t)l*CC, xn);
    float* tmp = (float*)xc; xc = xn; xn = tmp;
  }

  double* stF = stats + 16*32;
  k_final1<<<GB_E, 256, 0, stream>>>(xc, ei, We, be, stF);
  k_final2<<<GB_E, 256, 0, stream>>>(xc, ei, We, be, stF, ge, bte, out, lossd);
  k_final3<<<1, 1, 0, stream>>>(out, lossd);
}

// Round 3
// 1302.975 us; speedup vs baseline: 1.5696x; 1.1437x over previous
//
#include <hip/hip_runtime.h>
#include <cstdint>
#include <cstddef>

#define NN 100000
#define EE 400000
#define CC 16
#define LL 16

// ---------- device helpers ----------
__device__ __forceinline__ float lrelu(float v){ return v > 0.0f ? v : 0.01f*v; }

__device__ __forceinline__ float waveSum(float v){
#pragma unroll
  for (int off = 32; off >= 1; off >>= 1) v += __shfl_xor(v, off);
  return v;
}

__device__ __forceinline__ float fma4(float4 w, float4 v, float a){
  a = fmaf(w.x, v.x, a); a = fmaf(w.y, v.y, a);
  a = fmaf(w.z, v.z, a); a = fmaf(w.w, v.w, a);
  return a;
}

// ---------- init: count degrees (int atomics only) ----------
__global__ __launch_bounds__(256) void k_count(const int* __restrict__ ei,
    int* __restrict__ cdst, int* __restrict__ call)
{
  int t = blockIdx.x*256 + threadIdx.x;
  if (t >= EE) return;
  int s = ei[t], d = ei[EE + t];
  atomicAdd(&cdst[d], 1);
  atomicAdd(&call[s], 1);
  atomicAdd(&call[d], 1);
}

// ---------- generic exclusive scan (SEG=1024/block) ----------
__global__ __launch_bounds__(256) void k_scan1(const int* __restrict__ cnt,
    int* __restrict__ rp, int* __restrict__ bsums, int n)
{
  __shared__ int sd[256];
  int tid = threadIdx.x;
  int base = blockIdx.x*1024 + tid*4;
  int v0=0,v1=0,v2=0,v3=0;
  if (base+0 < n) v0 = cnt[base+0];
  if (base+1 < n) v1 = cnt[base+1];
  if (base+2 < n) v2 = cnt[base+2];
  if (base+3 < n) v3 = cnt[base+3];
  int tot = v0+v1+v2+v3;
  sd[tid] = tot; __syncthreads();
  for (int off=1; off<256; off<<=1){
    int add = (tid>=off) ? sd[tid-off] : 0;
    __syncthreads();
    sd[tid] += add;
    __syncthreads();
  }
  int excl = sd[tid] - tot;
  if (base+0 < n) rp[base+0] = excl;
  if (base+1 < n) rp[base+1] = excl+v0;
  if (base+2 < n) rp[base+2] = excl+v0+v1;
  if (base+3 < n) rp[base+3] = excl+v0+v1+v2;
  if (tid==255) bsums[blockIdx.x] = sd[255];
}

__global__ __launch_bounds__(256) void k_scan2(const int* __restrict__ bsums,
    int* __restrict__ boff, int nseg)
{
  __shared__ int sd[256];
  int tid = threadIdx.x;
  int v = (tid < nseg) ? bsums[tid] : 0;
  sd[tid] = v; __syncthreads();
  for (int off=1; off<256; off<<=1){
    int add = (tid>=off) ? sd[tid-off] : 0;
    __syncthreads();
    sd[tid] += add;
    __syncthreads();
  }
  if (tid < nseg) boff[tid] = sd[tid] - v;
}

__global__ __launch_bounds__(256) void k_scan3(int* __restrict__ rp,
    int* __restrict__ cur, const int* __restrict__ boff, int n, int total)
{
  int add = boff[blockIdx.x];
  int base = blockIdx.x*1024 + threadIdx.x*4;
#pragma unroll
  for (int i=0;i<4;i++){
    if (base+i < n){ int v = rp[base+i] + add; rp[base+i] = v; cur[base+i] = v; }
  }
  if (blockIdx.x==0 && threadIdx.x==0) rp[n] = total;
}

// ---------- fill both CSRs ----------
__global__ __launch_bounds__(256) void k_fill(const int* __restrict__ ei,
    int* __restrict__ cur, int* __restrict__ list,
    int* __restrict__ cur_all, int* __restrict__ list_all)
{
  int t = blockIdx.x*256 + threadIdx.x;
  if (t >= EE) return;
  int s = ei[t], d = ei[EE + t];
  int p = atomicAdd(&cur[d], 1);
  list[p] = t;
  int pa = atomicAdd(&cur_all[s], 1);
  list_all[pa] = t;
  int pb = atomicAdd(&cur_all[d], 1);
  list_all[pb] = t;
}

// ---------- permuted (dst-sorted) src/dst arrays: sequential writes ----------
__global__ __launch_bounds__(256) void k_perm(const int* __restrict__ ei,
    const int* __restrict__ list, int* __restrict__ sperm, int* __restrict__ dperm)
{
  int i = blockIdx.x*256 + threadIdx.x;
  if (i >= EE) return;
  int e = list[i];
  sperm[i] = ei[e];
  dperm[i] = ei[EE + e];
}

// ---------- x0 = mean of incident edge features; invdeg = 1/clip(deg_in,1) ----------
__global__ __launch_bounds__(256) void k_gather0(const float* __restrict__ ef,
    const int* __restrict__ rp_all, const int* __restrict__ list_all,
    const int* __restrict__ rp, float* __restrict__ x0, float* __restrict__ invdeg)
{
  int t = blockIdx.x*256 + threadIdx.x;
  if (t >= NN*CC) return;
  int n = t >> 4, c = t & 15;
  int beg = rp_all[n], end = rp_all[n+1];
  float acc = 0.0f;
  for (int i=beg; i<end; i++){
    acc += ef[(size_t)list_all[i]*CC + c];
  }
  float dg = fmaxf((float)(end-beg), 1.0f);
  x0[t] = acc / dg;
  if (c == 0){
    int di = rp[n+1] - rp[n];
    invdeg[n] = 1.0f / fmaxf((float)di, 1.0f);
  }
}

// ---------- per-layer: m[i] = W @ cat(x[dperm[i]],x[sperm[i]]) + b (permuted order) ----------
__global__ __launch_bounds__(256) void k_edge(const float* __restrict__ x,
    const int* __restrict__ sperm, const int* __restrict__ dperm,
    const float* __restrict__ W, const float* __restrict__ b,
    float* __restrict__ m, double* __restrict__ st)
{
  __shared__ float sW[512];
  __shared__ float sb16[16];
  __shared__ float sredS[64], sredQ[64];
  for (int i=threadIdx.x; i<512; i+=256) sW[i] = W[i];
  if (threadIdx.x < 16) sb16[threadIdx.x] = b[threadIdx.x];
  __syncthreads();

  int t = blockIdx.x*256 + threadIdx.x;
  int e0 = 2*t, e1 = 2*t+1;
  bool val = (e1 < EE);
  float acc0[16], acc1[16];
  if (val){
    int d0 = dperm[e0], s0 = sperm[e0], d1 = dperm[e1], s1 = sperm[e1];
    float4 xc0[8], xc1[8];
    const float4* p;
    p = (const float4*)(x + (size_t)d0*CC); xc0[0]=p[0]; xc0[1]=p[1]; xc0[2]=p[2]; xc0[3]=p[3];
    p = (const float4*)(x + (size_t)s0*CC); xc0[4]=p[0]; xc0[5]=p[1]; xc0[6]=p[2]; xc0[7]=p[3];
    p = (const float4*)(x + (size_t)d1*CC); xc1[0]=p[0]; xc1[1]=p[1]; xc1[2]=p[2]; xc1[3]=p[3];
    p = (const float4*)(x + (size_t)s1*CC); xc1[4]=p[0]; xc1[5]=p[1]; xc1[6]=p[2]; xc1[7]=p[3];
#pragma unroll
    for (int c=0;c<CC;c++){
      const float4* wr = (const float4*)(sW + c*32);
      float a0 = sb16[c], a1 = sb16[c];
#pragma unroll
      for (int q=0;q<8;q++){
        float4 w = wr[q];
        a0 = fma4(w, xc0[q], a0);
        a1 = fma4(w, xc1[q], a1);
      }
      acc0[c]=a0; acc1[c]=a1;
    }
    float4* mo0 = (float4*)(m + (size_t)e0*CC);
    float4* mo1 = (float4*)(m + (size_t)e1*CC);
    mo0[0]=make_float4(acc0[0],acc0[1],acc0[2],acc0[3]);
    mo0[1]=make_float4(acc0[4],acc0[5],acc0[6],acc0[7]);
    mo0[2]=make_float4(acc0[8],acc0[9],acc0[10],acc0[11]);
    mo0[3]=make_float4(acc0[12],acc0[13],acc0[14],acc0[15]);
    mo1[0]=make_float4(acc1[0],acc1[1],acc1[2],acc1[3]);
    mo1[1]=make_float4(acc1[4],acc1[5],acc1[6],acc1[7]);
    mo1[2]=make_float4(acc1[8],acc1[9],acc1[10],acc1[11]);
    mo1[3]=make_float4(acc1[12],acc1[13],acc1[14],acc1[15]);
  } else {
#pragma unroll
    for (int c=0;c<CC;c++){ acc0[c]=0.0f; acc1[c]=0.0f; }
  }

  int lane = threadIdx.x & 63, w = threadIdx.x >> 6;
#pragma unroll
  for (int c=0;c<CC;c++){
    float rs = acc0[c] + acc1[c];
    float rq = acc0[c]*acc0[c] + acc1[c]*acc1[c];
    rs = waveSum(rs); rq = waveSum(rq);
    if (lane == 0){ sredS[w*16+c] = rs; sredQ[w*16+c] = rq; }
  }
  __syncthreads();
  if (threadIdx.x < 16){
    int c = threadIdx.x;
    float tot = sredS[c] + sredS[16+c] + sredS[32+c] + sredS[48+c];
    unsafeAtomicAdd(&st[c], (double)tot);
  } else if (threadIdx.x < 32){
    int c = threadIdx.x - 16;
    float tot = sredQ[c] + sredQ[16+c] + sredQ[32+c] + sredQ[48+c];
    unsafeAtomicAdd(&st[16+c], (double)tot);
  }
}

// ---------- per-layer: finalize BN, leaky, contiguous segment-mean by dst ----------
__global__ __launch_bounds__(256) void k_node(const float* __restrict__ m,
    const int* __restrict__ rp,
    const float* __restrict__ invdeg, const double* __restrict__ st,
    const float* __restrict__ g, const float* __restrict__ bt,
    float* __restrict__ xout)
{
  __shared__ float sA[16], sB[16];
  if (threadIdx.x < 16){
    int c = threadIdx.x;
    double mu  = st[c] * (1.0/EE);
    double var = st[16+c] * (1.0/EE) - mu*mu;
    float sc = rsqrtf((float)var + 1e-5f);
    float A = sc * g[c];
    sA[c] = A; sB[c] = bt[c] - (float)mu * A;
  }
  __syncthreads();
  int t = blockIdx.x*256 + threadIdx.x;
  int n = t >> 4, c = t & 15;
  if (n >= NN) return;
  float A = sA[c], B = sB[c];
  int beg = rp[n], end = rp[n+1];
  float acc = 0.0f;
  for (int i=beg; i<end; i++){
    acc += lrelu(fmaf(A, m[(size_t)i*CC + c], B));
  }
  xout[t] = acc * invdeg[n];
}

// ---------- final stage 1: BN stats over 2E rows (both orientations) ----------
__global__ __launch_bounds__(256) void k_final1(const float* __restrict__ x,
    const int* __restrict__ ei, const float* __restrict__ W, const float* __restrict__ b,
    double* __restrict__ st)
{
  __shared__ float sW[512];
  __shared__ float sb16[16];
  __shared__ float sredS[64], sredQ[64];
  for (int i=threadIdx.x; i<512; i+=256) sW[i] = W[i];
  if (threadIdx.x < 16) sb16[threadIdx.x] = b[threadIdx.x];
  __syncthreads();

  int t = blockIdx.x*256 + threadIdx.x;
  bool val = (t < EE);
  float af[16], ab[16];
  if (val){
    int s = ei[t], d = ei[EE+t];
    float4 xs[4], xd[4];
    const float4* p;
    p = (const float4*)(x + (size_t)s*CC); xs[0]=p[0]; xs[1]=p[1]; xs[2]=p[2]; xs[3]=p[3];
    p = (const float4*)(x + (size_t)d*CC); xd[0]=p[0]; xd[1]=p[1]; xd[2]=p[2]; xd[3]=p[3];
#pragma unroll
    for (int c=0;c<CC;c++){
      const float4* wr = (const float4*)(sW + c*32);
      float f = sb16[c], g_ = sb16[c];
#pragma unroll
      for (int q=0;q<4;q++){ float4 w = wr[q];   f = fma4(w, xs[q], f);  g_ = fma4(w, xd[q], g_); }
#pragma unroll
      for (int q=0;q<4;q++){ float4 w = wr[4+q]; f = fma4(w, xd[q], f);  g_ = fma4(w, xs[q], g_); }
      af[c]=f; ab[c]=g_;
    }
  } else {
#pragma unroll
    for (int c=0;c<CC;c++){ af[c]=0.0f; ab[c]=0.0f; }
  }

  int lane = threadIdx.x & 63, w = threadIdx.x >> 6;
#pragma unroll
  for (int c=0;c<CC;c++){
    float rs = af[c] + ab[c];
    float rq = af[c]*af[c] + ab[c]*ab[c];
    rs = waveSum(rs); rq = waveSum(rq);
    if (lane == 0){ sredS[w*16+c] = rs; sredQ[w*16+c] = rq; }
  }
  __syncthreads();
  if (threadIdx.x < 16){
    int c = threadIdx.x;
    float tot = sredS[c] + sredS[16+c] + sredS[32+c] + sredS[48+c];
    unsafeAtomicAdd(&st[c], (double)tot);
  } else if (threadIdx.x < 32){
    int c = threadIdx.x - 16;
    float tot = sredQ[c] + sredQ[16+c] + sredQ[32+c] + sredQ[48+c];
    unsafeAtomicAdd(&st[16+c], (double)tot);
  }
}

// ---------- final stage 2: recompute, BN+leaky, edge_out + loss accumulation ----------
__global__ __launch_bounds__(256) void k_final2(const float* __restrict__ x,
    const int* __restrict__ ei, const float* __restrict__ W, const float* __restrict__ b,
    const double* __restrict__ st, const float* __restrict__ g, const float* __restrict__ bt,
    float* __restrict__ out, double* __restrict__ loss)
{
  __shared__ float sW[512];
  __shared__ float sb16[16];
  __shared__ float sA[16], sB[16];
  __shared__ float sl[4];
  for (int i=threadIdx.x; i<512; i+=256) sW[i] = W[i];
  if (threadIdx.x < 16){
    int c = threadIdx.x;
    sb16[c] = b[c];
    double mu  = st[c] * (1.0/(2.0*EE));
    double var = st[16+c] * (1.0/(2.0*EE)) - mu*mu;
    float sc = rsqrtf((float)var + 1e-5f);
    float A = sc * g[c];
    sA[c] = A; sB[c] = bt[c] - (float)mu * A;
  }
  __syncthreads();

  int t = blockIdx.x*256 + threadIdx.x;
  bool val = (t < EE);
  float lsum = 0.0f;
  if (val){
    int s = ei[t], d = ei[EE+t];
    float4 xs[4], xd[4];
    const float4* p;
    p = (const float4*)(x + (size_t)s*CC); xs[0]=p[0]; xs[1]=p[1]; xs[2]=p[2]; xs[3]=p[3];
    p = (const float4*)(x + (size_t)d*CC); xd[0]=p[0]; xd[1]=p[1]; xd[2]=p[2]; xd[3]=p[3];
    float fo[16];
#pragma unroll
    for (int c=0;c<CC;c++){
      const float4* wr = (const float4*)(sW + c*32);
      float f = sb16[c], g_ = sb16[c];
#pragma unroll
      for (int q=0;q<4;q++){ float4 w = wr[q];   f = fma4(w, xs[q], f);  g_ = fma4(w, xd[q], g_); }
#pragma unroll
      for (int q=0;q<4;q++){ float4 w = wr[4+q]; f = fma4(w, xd[q], f);  g_ = fma4(w, xs[q], g_); }
      float efv = lrelu(fmaf(sA[c], f,  sB[c]));
      float ebv = lrelu(fmaf(sA[c], g_, sB[c]));
      fo[c] = 0.5f*(efv + ebv);
      float dlt = efv - ebv;
      lsum = fmaf(dlt, dlt, lsum);
    }
    float4* po = (float4*)(out + (size_t)t*CC);
    po[0]=make_float4(fo[0],fo[1],fo[2],fo[3]);
    po[1]=make_float4(fo[4],fo[5],fo[6],fo[7]);
    po[2]=make_float4(fo[8],fo[9],fo[10],fo[11]);
    po[3]=make_float4(fo[12],fo[13],fo[14],fo[15]);
  }
  lsum = waveSum(lsum);
  int lane = threadIdx.x & 63, w = threadIdx.x >> 6;
  if (lane == 0) sl[w] = lsum;
  __syncthreads();
  if (threadIdx.x == 0)
    unsafeAtomicAdd(loss, (double)(sl[0]+sl[1]+sl[2]+sl[3]));
}

__global__ void k_final3(float* __restrict__ out, const double* __restrict__ loss)
{
  out[(size_t)EE*CC] = (float)(loss[0] * (1.0/((double)EE*CC)));
}

// ---------- host ----------
extern "C" void kernel_launch(void* const* d_in, const int* in_sizes, int n_in,
                              void* d_out, int out_size, void* d_ws, size_t ws_size,
                              hipStream_t stream)
{
  (void)in_sizes; (void)n_in; (void)out_size; (void)ws_size;
  const float* ef  = (const float*)d_in[0];
  const int*   ei  = (const int*)d_in[1];
  // d_in[2] = angles (unused by reference forward)
  const float* Wn  = (const float*)d_in[3];
  const float* bn  = (const float*)d_in[4];
  const float* gn  = (const float*)d_in[5];
  const float* btn = (const float*)d_in[6];
  const float* We  = (const float*)d_in[7];
  const float* be  = (const float*)d_in[8];
  const float* ge  = (const float*)d_in[9];
  const float* bte = (const float*)d_in[10];
  float* out = (float*)d_out;
  char* ws = (char*)d_ws;

  size_t off = 0;
  auto alloc = [&](size_t bytes)->size_t{
    size_t r = off; off = (off + bytes + 255) & ~(size_t)255; return r;
  };
  size_t o_xa     = alloc((size_t)NN*CC*4);
  size_t o_xb     = alloc((size_t)NN*CC*4);
  size_t o_m      = alloc((size_t)EE*CC*4);
  size_t o_cdst   = alloc((size_t)NN*4);
  size_t o_call   = alloc((size_t)NN*4);
  size_t o_rp     = alloc((size_t)(NN+1)*4);
  size_t o_rpall  = alloc((size_t)(NN+1)*4);
  size_t o_cur    = alloc((size_t)NN*4);
  size_t o_curall = alloc((size_t)NN*4);
  size_t o_list   = alloc((size_t)EE*4);
  size_t o_listall= alloc((size_t)2*EE*4);
  size_t o_sperm  = alloc((size_t)EE*4);
  size_t o_dperm  = alloc((size_t)EE*4);
  size_t o_bsum   = alloc(512);
  size_t o_boff   = alloc(512);
  size_t o_stats  = alloc(545*8);   // 17 slots * 32 doubles + 1 loss double
  size_t o_invdeg = alloc((size_t)NN*4);

  float*  x_a     = (float*)(ws + o_xa);
  float*  x_b     = (float*)(ws + o_xb);
  float*  m_hat   = (float*)(ws + o_m);
  int*    cdst    = (int*)(ws + o_cdst);
  int*    call_   = (int*)(ws + o_call);
  int*    rp      = (int*)(ws + o_rp);
  int*    rp_all  = (int*)(ws + o_rpall);
  int*    cur     = (int*)(ws + o_cur);
  int*    cur_all = (int*)(ws + o_curall);
  int*    list    = (int*)(ws + o_list);
  int*    list_all= (int*)(ws + o_listall);
  int*    sperm   = (int*)(ws + o_sperm);
  int*    dperm   = (int*)(ws + o_dperm);
  int*    bsum    = (int*)(ws + o_bsum);
  int*    boff    = (int*)(ws + o_boff);
  double* stats   = (double*)(ws + o_stats);
  double* lossd   = stats + 17*32;   // index 544
  float*  invdeg  = (float*)(ws + o_invdeg);

  const int GB_E  = (EE + 255)/256;       // 1563
  const int GB_E2 = (EE/2 + 255)/256;     // 782
  const int GB_NC = (NN*CC + 255)/256;    // 6250
  const int NSEG  = (NN + 1023)/1024;     // 98

  hipMemsetAsync(cdst, 0, (size_t)NN*4, stream);
  hipMemsetAsync(call_, 0, (size_t)NN*4, stream);
  hipMemsetAsync(stats, 0, 545*8, stream);

  k_count<<<GB_E, 256, 0, stream>>>(ei, cdst, call_);
  // dst CSR
  k_scan1<<<NSEG, 256, 0, stream>>>(cdst, rp, bsum, NN);
  k_scan2<<<1, 256, 0, stream>>>(bsum, boff, NSEG);
  k_scan3<<<NSEG, 256, 0, stream>>>(rp, cur, boff, NN, EE);
  // all CSR
  k_scan1<<<NSEG, 256, 0, stream>>>(call_, rp_all, bsum, NN);
  k_scan2<<<1, 256, 0, stream>>>(bsum, boff, NSEG);
  k_scan3<<<NSEG, 256, 0, stream>>>(rp_all, cur_all, boff, NN, 2*EE);
  // fill both lists
  k_fill<<<GB_E, 256, 0, stream>>>(ei, cur, list, cur_all, list_all);
  // permuted (dst-sorted) endpoint arrays
  k_perm<<<GB_E, 256, 0, stream>>>(ei, list, sperm, dperm);
  // initial node features (gather-mean) + invdeg
  k_gather0<<<GB_NC, 256, 0, stream>>>(ef, rp_all, list_all, rp, x_a, invdeg);

  const float* xc = x_a;
  float* xn = x_b;
  for (int l = 0; l < LL; ++l){
    double* st = stats + (size_t)l*32;
    k_edge<<<GB_E2, 256, 0, stream>>>(xc, sperm, dperm, Wn + (size_t)l*CC*2*CC, bn + (size_t)l*CC, m_hat, st);
    k_node<<<GB_NC, 256, 0, stream>>>(m_hat, rp, invdeg, st, gn + (size_t)l*CC, btn + (size_t)l*CC, xn);
    float* tmp = (float*)xc; xc = xn; xn = tmp;
  }

  double* stF = stats + 16*32;
  k_final1<<<GB_E, 256, 0, stream>>>(xc, ei, We, be, stF);
  k_final2<<<GB_E, 256, 0, stream>>>(xc, ei, We, be, stF, ge, bte, out, lossd);
  k_final3<<<1, 1, 0, stream>>>(out, lossd);
}